// Round 1
// 143.660 us; speedup vs baseline: 1.0501x; 1.0501x over previous
//
#include <hip/hip_runtime.h>
#include <hip/hip_bf16.h>

// Causal linear attention, chunked decomposition.
// B=4 H=16 T=2048 D=64. Chunk C=256, NC=8 chunks, BH=64 batch-heads.
// Kernel 1: per-(bh,chunk) KV state  KV_c = K_c^T V_c  (64x64 fp32) -> ws
// Kernel 2: per-(bh,chunk) output    O = Q_c * prefixKV + tril(Q_c K_c^T) V_c
// bf16 MFMA (16x16x32), fp32 accumulate. Threshold 36.96 >> bf16 error (~3).
//
// R1 rewrite: latency-bound fix.
//  - S computed as S^T (swap MFMA operands; A-frag(X) == B-frag(X^T)) so each
//    lane holds 4 contiguous s-values -> packed ds_write_b64 into per-wave Sw,
//    and ALL 20 block barriers around Sw are deleted (wave-private buffer,
//    intra-wave LDS ordering via lgkmcnt suffices).
//  - K staged row-major with b128 writes; V transposed via 4x4 register
//    transpose -> b64 writes. Zero scalar ds_write_b16 remain.
//  - Kj/VTj (and kv-kernel KT/VT) double-buffered, loads issued early and
//    LDS writes placed late (T14): 1 barrier per tile instead of 2.
// Barriers per attn block: 30 -> 4.

#define B_   4
#define H_   16
#define T_   2048
#define D_   64
#define BH_  64
#define CCH  256
#define NCH  8
#define LPAD 8
#define LW   (D_ + LPAD)   // 72 bf16 = 144 B row stride (16B aligned; the +16B
                           // pad rotates 16B-blocks across rows -> conflict-free
                           // b128 fragment reads)

typedef __bf16 bf16x4 __attribute__((ext_vector_type(4)));
typedef __bf16 bf16x8 __attribute__((ext_vector_type(8)));
typedef float  f32x4  __attribute__((ext_vector_type(4)));

// MFMA fragment layouts (16x16x32 bf16, HW-verified per guide):
//   A: A[m = lane&15][k = (lane>>4)*8 + j]   (8 contiguous k per lane)
//   B: B[k = (lane>>4)*8 + j][n = lane&15]
//   C/D: row = (lane>>4)*4 + reg, col = lane&15
// Mirror property: a row-major contiguous 8-elem load of X rows is both the
// A-fragment of X and the B-fragment of X^T.

__global__ __launch_bounds__(256, 2) void kv_chunk_kernel(
    const float* __restrict__ k, const float* __restrict__ v,
    float* __restrict__ kvws) {
  __shared__ __align__(16) __bf16 KT[2][D_][LW];  // [d][s] transposed, dbuf
  __shared__ __align__(16) __bf16 VT[2][D_][LW];  // [d][s] transposed, dbuf

  const int tid  = threadIdx.x;
  const int lane = tid & 63;
  const int w    = tid >> 6;
  const int quad = lane >> 4;
  const int l15  = lane & 15;
  const int bh   = blockIdx.x >> 3;
  const int c    = blockIdx.x & (NCH - 1);
  const long base = ((long)bh * T_ + (long)c * CCH) * D_;

  // 4x4 register-transpose staging: thread (s4,d4) owns a 4x4 tile.
  const int s4 = tid >> 4;   // 0..15 -> s-block of 4
  const int d4 = tid & 15;   // 0..15 -> d-block of 4

  f32x4 kreg[4], vreg[4];
  const float* kp0 = k + base + (long)(s4 * 4) * D_ + d4 * 4;
  const float* vp0 = v + base + (long)(s4 * 4) * D_ + d4 * 4;

  auto LOAD = [&](int st) {
#pragma unroll
    for (int r = 0; r < 4; ++r) {
      kreg[r] = *(const f32x4*)(kp0 + (long)(st * 64 + r) * D_);
      vreg[r] = *(const f32x4*)(vp0 + (long)(st * 64 + r) * D_);
    }
  };
  auto WRITE = [&](int p) {
#pragma unroll
    for (int cc2 = 0; cc2 < 4; ++cc2) {
      bf16x4 ka, va;
#pragma unroll
      for (int r = 0; r < 4; ++r) {
        ka[r] = (__bf16)kreg[r][cc2];
        va[r] = (__bf16)vreg[r][cc2];
      }
      *(bf16x4*)&KT[p][d4 * 4 + cc2][s4 * 4] = ka;
      *(bf16x4*)&VT[p][d4 * 4 + cc2][s4 * 4] = va;
    }
  };

  const f32x4 vzero = {0.f, 0.f, 0.f, 0.f};
  f32x4 acc[4];
#pragma unroll
  for (int n = 0; n < 4; ++n) acc[n] = vzero;

  LOAD(0);
  WRITE(0);
  __syncthreads();
  for (int st = 0; st < 4; ++st) {  // 4 s-tiles of 64 cover the 256 chunk
    const int p = st & 1;
    if (st < 3) LOAD(st + 1);  // issue early; write after compute
    // KV[d1][d2] += sum_s K[s][d1]*V[s][d2]; wave w owns d1 rows [16w,16w+16)
#pragma unroll
    for (int ks = 0; ks < 2; ++ks) {
      bf16x8 a = *(const bf16x8*)&KT[p][w * 16 + l15][ks * 32 + quad * 8];
#pragma unroll
      for (int n = 0; n < 4; ++n) {
        bf16x8 b = *(const bf16x8*)&VT[p][n * 16 + l15][ks * 32 + quad * 8];
        acc[n] = __builtin_amdgcn_mfma_f32_16x16x32_bf16(a, b, acc[n], 0, 0, 0);
      }
    }
    if (st < 3) {
      WRITE(p ^ 1);
      __syncthreads();
    }
  }
  float* out = kvws + ((long)blockIdx.x << 12);  // 64*64 fp32 per (bh,c)
#pragma unroll
  for (int n = 0; n < 4; ++n)
#pragma unroll
    for (int rr = 0; rr < 4; ++rr)
      out[(w * 16 + quad * 4 + rr) * 64 + n * 16 + l15] = acc[n][rr];
}

__global__ __launch_bounds__(256, 2) void attn_chunk_kernel(
    const float* __restrict__ q, const float* __restrict__ k,
    const float* __restrict__ v, const float* __restrict__ kvws,
    float* __restrict__ out) {
  __shared__ __align__(16) __bf16 KVT[D_][LW];     // KVsum transposed [d2][d1]
  __shared__ __align__(16) __bf16 Kj[2][64][LW];   // key subtile [s][d], dbuf
  __shared__ __align__(16) __bf16 VTj[2][D_][LW];  // value subtile [d][s], dbuf
  __shared__ __align__(16) __bf16 Sw[4][16][LW];   // per-wave S tile [m][s]

  const int tid  = threadIdx.x;
  const int lane = tid & 63;
  const int w    = tid >> 6;
  const int quad = lane >> 4;
  const int l15  = lane & 15;
  const int bh   = blockIdx.x >> 3;
  const int c    = blockIdx.x & (NCH - 1);
  const long base = ((long)bh * T_ + (long)c * CCH) * D_;

  // staging thread mappings
  const int slK = tid >> 2;          // K: one row per thread
  const int d0K = (tid & 3) * 16;    // K: 16 cols per thread
  const int s4  = tid >> 4;          // V: 4x4 tile, s-block
  const int d4  = tid & 15;          // V: 4x4 tile, d-block

  f32x4 kreg[4], vreg[4];
  auto LOADJ = [&](int j) {
    const float* kp = k + base + (long)(j * 64 + slK) * D_ + d0K;
    const float* vp = v + base + (long)(j * 64 + s4 * 4) * D_ + d4 * 4;
#pragma unroll
    for (int r = 0; r < 4; ++r) kreg[r] = *(const f32x4*)(kp + r * 4);
#pragma unroll
    for (int r = 0; r < 4; ++r) vreg[r] = *(const f32x4*)(vp + (long)r * D_);
  };
  auto WRITEJ = [&](int p) {
    bf16x8 kb0, kb1;
#pragma unroll
    for (int e = 0; e < 4; ++e) {
      kb0[e]     = (__bf16)kreg[0][e];
      kb0[4 + e] = (__bf16)kreg[1][e];
      kb1[e]     = (__bf16)kreg[2][e];
      kb1[4 + e] = (__bf16)kreg[3][e];
    }
    *(bf16x8*)&Kj[p][slK][d0K]     = kb0;
    *(bf16x8*)&Kj[p][slK][d0K + 8] = kb1;
#pragma unroll
    for (int cc2 = 0; cc2 < 4; ++cc2) {
      bf16x4 va;
#pragma unroll
      for (int r = 0; r < 4; ++r) va[r] = (__bf16)vreg[r][cc2];
      *(bf16x4*)&VTj[p][d4 * 4 + cc2][s4 * 4] = va;
    }
  };

  // ---- 1. prefix-sum KV states of prior chunks -> KVT (bf16, transposed)
  // thread owns linear range [tid*16, tid*16+16): contiguous dwordx4 loads.
  float kvacc[16];
#pragma unroll
  for (int i = 0; i < 16; ++i) kvacc[i] = 0.f;
  const float* wsbh = kvws + ((long)(bh * NCH) << 12);
  for (int cc = 0; cc < c; ++cc) {
    const float* pp = wsbh + ((long)cc << 12) + tid * 16;
#pragma unroll
    for (int x = 0; x < 4; ++x) {
      f32x4 t = *(const f32x4*)(pp + x * 4);
#pragma unroll
      for (int e = 0; e < 4; ++e) kvacc[x * 4 + e] += t[e];
    }
  }
  {
    const int d1  = tid >> 2;          // lin = tid*16+ii: d1 = lin>>6
    const int d2b = (tid & 3) * 16;    //                  d2 = d2b+ii
#pragma unroll
    for (int ii = 0; ii < 16; ++ii) KVT[d2b + ii][d1] = (__bf16)kvacc[ii];
  }

  // ---- 2. Q A-fragments in registers. wave w owns M-tiles {w, w+4, w+8, w+12}
  bf16x8 qf[4][2];
#pragma unroll
  for (int i = 0; i < 4; ++i) {
    int row = (w + 4 * i) * 16 + l15;
    const float* qp = q + base + (long)row * D_ + quad * 8;
#pragma unroll
    for (int ks = 0; ks < 2; ++ks) {
      f32x4 lo = *(const f32x4*)(qp + ks * 32);
      f32x4 hi = *(const f32x4*)(qp + ks * 32 + 4);
      bf16x8 f;
#pragma unroll
      for (int e = 0; e < 4; ++e) {
        f[e]     = (__bf16)lo[e];
        f[4 + e] = (__bf16)hi[e];
      }
      qf[i][ks] = f;
    }
  }

  const f32x4 vzero = {0.f, 0.f, 0.f, 0.f};
  f32x4 acc[4][4];
#pragma unroll
  for (int i = 0; i < 4; ++i)
#pragma unroll
    for (int n = 0; n < 4; ++n) acc[i][n] = vzero;

  LOADJ(0);
  WRITEJ(0);
  __syncthreads();  // KVT + tile-0 staging ready
  LOADJ(1);         // prefetch j=1 under the inter-chunk matmul

  // ---- 3. inter-chunk: O += Q @ KVsum   (zeros when c==0; uniform work)
#pragma unroll
  for (int ks = 0; ks < 2; ++ks)
#pragma unroll
    for (int n = 0; n < 4; ++n) {
      bf16x8 b = *(const bf16x8*)&KVT[n * 16 + l15][ks * 32 + quad * 8];
#pragma unroll
      for (int i = 0; i < 4; ++i)
        acc[i][n] =
            __builtin_amdgcn_mfma_f32_16x16x32_bf16(qf[i][ks], b, acc[i][n], 0, 0, 0);
    }

  // ---- 4. intra-chunk causal part over 4 key subtiles of 64
  for (int j = 0; j < 4; ++j) {
    const int p = j & 1;
    // hoist K/V fragments for this subtile (reused across all i)
    bf16x8 kfrag[2][4], vfrag[2][4];
#pragma unroll
    for (int ks = 0; ks < 2; ++ks)
#pragma unroll
      for (int n = 0; n < 4; ++n) {
        kfrag[ks][n] = *(const bf16x8*)&Kj[p][n * 16 + l15][ks * 32 + quad * 8];
        vfrag[ks][n] = *(const bf16x8*)&VTj[p][n * 16 + l15][ks * 32 + quad * 8];
      }
    // M-tile (w+4i) needs key subtile j iff i >= j; i==j is the masked diagonal.
    for (int i = j; i < 4; ++i) {
      f32x4 s[4];
#pragma unroll
      for (int n = 0; n < 4; ++n) s[n] = vzero;
      // S^T = K Q^T: A = K-frag, B = Q-frag (mirror property).
      // C layout: s_in64 = n*16 + quad*4 + rr, q_local = l15.
#pragma unroll
      for (int ks = 0; ks < 2; ++ks)
#pragma unroll
        for (int n = 0; n < 4; ++n)
          s[n] = __builtin_amdgcn_mfma_f32_16x16x32_bf16(kfrag[ks][n], qf[i][ks],
                                                         s[n], 0, 0, 0);
      // mask + pack 4 contiguous s-values -> one b64 store per n (wave-private
      // Sw: no block barrier needed, intra-wave LDS ordering suffices).
#pragma unroll
      for (int n = 0; n < 4; ++n) {
        bf16x4 pk;
#pragma unroll
        for (int rr = 0; rr < 4; ++rr) {
          float val = s[n][rr];
          if (i == j && (n * 16 + quad * 4 + rr > 16 * w + l15)) val = 0.f;
          pk[rr] = (__bf16)val;
        }
        *(bf16x4*)&Sw[w][l15][n * 16 + quad * 4] = pk;
      }
#pragma unroll
      for (int ks = 0; ks < 2; ++ks) {
        bf16x8 a = *(const bf16x8*)&Sw[w][l15][ks * 32 + quad * 8];
#pragma unroll
        for (int n = 0; n < 4; ++n)
          acc[i][n] =
              __builtin_amdgcn_mfma_f32_16x16x32_bf16(a, vfrag[ks][n], acc[i][n], 0, 0, 0);
      }
    }
    if (j < 3) {
      WRITEJ(p ^ 1);      // write-late into the idle buffer
      __syncthreads();    // single barrier per subtile
      if (j < 2) LOADJ(j + 2);  // issue-early next tile's loads
    }
  }

  // ---- 5. epilogue: write O (fp32)
  float* op = out + base;
#pragma unroll
  for (int i = 0; i < 4; ++i) {
    int row = (w + 4 * i) * 16 + quad * 4;
#pragma unroll
    for (int n = 0; n < 4; ++n)
#pragma unroll
      for (int rr = 0; rr < 4; ++rr)
        op[(long)(row + rr) * D_ + n * 16 + l15] = acc[i][n][rr];
  }
}

extern "C" void kernel_launch(void* const* d_in, const int* in_sizes, int n_in,
                              void* d_out, int out_size, void* d_ws, size_t ws_size,
                              hipStream_t stream) {
  const float* q = (const float*)d_in[0];
  const float* k = (const float*)d_in[1];
  const float* v = (const float*)d_in[2];
  float* out = (float*)d_out;
  float* kvws = (float*)d_ws;  // needs BH_*NCH*64*64*4 = 8 MiB

  hipLaunchKernelGGL(kv_chunk_kernel, dim3(BH_ * NCH), dim3(256), 0, stream,
                     k, v, kvws);
  hipLaunchKernelGGL(attn_chunk_kernel, dim3(BH_ * NCH), dim3(256), 0, stream,
                     q, k, v, kvws, out);
}